// Round 7
// baseline (558.093 us; speedup 1.0000x reference)
//
#include <hip/hip_runtime.h>
#include <hip/hip_bf16.h>

#define H 1024
#define S 1024
#define B 32
#define K2 2048  // 2*H

typedef unsigned short u16;
typedef __attribute__((ext_vector_type(8))) short short8;     // 8 bf16 (4 VGPRs) — MFMA A/B frag
typedef __attribute__((ext_vector_type(8))) unsigned short u16x8;
typedef __attribute__((ext_vector_type(4))) float floatx4;    // MFMA C/D frag

__device__ __forceinline__ u16 f2bf(float f) {
  unsigned u = __float_as_uint(f);
  u += 0x7FFFu + ((u >> 16) & 1u);   // RNE to bf16
  return (u16)(u >> 16);
}

// async global->LDS, 16B per lane; global addr is PER-LANE, LDS dest = wave-uniform base + lane*16
__device__ __forceinline__ void gld_lds16(const void* g, void* l) {
  __builtin_amdgcn_global_load_lds(
      (const __attribute__((address_space(1))) unsigned int*)g,
      (__attribute__((address_space(3))) unsigned int*)l, 16, 0, 0);
}

// fast tanh: 1 - 2/(e^{2x}+1). Exact +-1 asymptotes, ~6 VALU ops, |err| ~ 1e-7.
__device__ __forceinline__ float tanh_fast(float x) {
  float t = __expf(2.0f * x);
  return 1.0f - 2.0f / (t + 1.0f);
}

// W_attn (H,3H) fp32 -> W_e bf16 (H,2H)
__global__ void conv_we_k(const float* __restrict__ W, u16* __restrict__ dst) {
  const int h = blockIdx.x;
  const int t = threadIdx.x * 8;
  const float* sp = W + (size_t)h * 3072 + H + t;
  u16* dp = dst + (size_t)h * K2 + t;
  floatx4 x = *(const floatx4*)sp;
  floatx4 y = *(const floatx4*)(sp + 4);
  u16x8 o;
  o[0] = f2bf(x[0]); o[1] = f2bf(x[1]); o[2] = f2bf(x[2]); o[3] = f2bf(x[3]);
  o[4] = f2bf(y[0]); o[5] = f2bf(y[1]); o[6] = f2bf(y[2]); o[7] = f2bf(y[3]);
  *(u16x8*)dp = o;
}

// enc (S,B,2H) fp32 -> encb (B,S,2H) bf16. Pure BW pass (~384MB traffic).
__global__ void conv_enc_k(const float* __restrict__ enc, u16* __restrict__ dst) {
  const int sb = blockIdx.x;          // s*B + b
  const int s = sb >> 5;
  const int b = sb & 31;
  const int t = threadIdx.x * 8;
  const float* sp = enc + (size_t)sb * K2 + t;
  u16* dp = dst + ((size_t)b * S + s) * K2 + t;
  floatx4 x = *(const floatx4*)sp;
  floatx4 y = *(const floatx4*)(sp + 4);
  u16x8 o;
  o[0] = f2bf(x[0]); o[1] = f2bf(x[1]); o[2] = f2bf(x[2]); o[3] = f2bf(x[3]);
  o[4] = f2bf(y[0]); o[5] = f2bf(y[1]); o[6] = f2bf(y[2]); o[7] = f2bf(y[3]);
  *(u16x8*)dp = o;
}

// h_proj[b,h] = hidden[b,:] . W_attn[h, 0:H] + b_attn[h]   (fp32 exact path)
__global__ void hproj_k(const float* __restrict__ hidden, const float* __restrict__ W,
                        const float* __restrict__ b_attn, float* __restrict__ hp) {
  const int lane = threadIdx.x & 63;
  const int h = (blockIdx.x * blockDim.x + threadIdx.x) >> 6;
  float wr[16];
#pragma unroll
  for (int i = 0; i < 16; i++) wr[i] = W[(size_t)h * 3072 + lane + i * 64];
  for (int b = 0; b < B; b++) {
    float d = 0.f;
#pragma unroll
    for (int i = 0; i < 16; i++) d = fmaf(wr[i], hidden[b * H + lane + i * 64], d);
#pragma unroll
    for (int off = 32; off; off >>= 1) d += __shfl_xor(d, off);
    if (lane == 0) hp[b * H + h] = d + b_attn[h];
  }
}

// ===================== 256x256 4-phase GEMM (T2+T3+T4+T5) =====================
// 8 waves (2M x 4N), per-wave output 128x64, BK=64, 32 K-tiles, 2 tiles/iter.
// LDS 128KB: sA/sB x 2 bufs x 2 regions x (128 rows x 64 bf16).
// Round-7 change: merge phase pairs -> 4 phases/iter (Q1..Q4), 8 barriers
// instead of 16, 32 MFMA per phase, same 48 ds_read_b128/iter (16/8/16/8).
// bf0/bf1 persist in registers across the mh0->mh1 phase pair; af reloaded
// per phase. Walls (2 barriers + lgkm drain) amortize over 2x the MFMA.
// Stage rotation (region's last LDS read -> stage phase; all >=1 barrier apart):
//   sA[1][1]: read Q4 -> staged NEXT-iter Q1 (<-t1)     [2 loads]
//   sA[0][0]: read Q1 -> staged Q2 (<-t2)               [2 loads]
//   sA[0][1]: read Q2 -> staged Q3 (<-t2)               [2 loads]
//   sB[0][0],sB[0][1]: read Q1 -> staged Q3 (<-t2)      [4 loads]
//   sA[1][0],sB[1][0],sB[1][1]: read Q3 -> staged Q4 (<-t3)  [6 loads]
// vmcnt ledger (loads/thread): enter Q1 with prev-Q4's 6 in flight.
//   Q2-end: outstanding prevQ4(6)+Q1(2)+Q2(2)=10 -> vmcnt(2): buf1 fully
//           landed before Q3 (leaves Q2's 2).
//   Q4-end: outstanding Q2(2)+Q3(6)+Q4(6)=14 -> vmcnt(6): buf0(t2) landed
//           before next Q1 (leaves Q4's 6).  Last iter: Q2-end drains to 0.
// Prologue = buf0(t0) 8 loads + buf1(t1) {A10,B10,B11} 6 loads, vmcnt(6):
// exactly the steady-state entry condition.
#define BM 256
#define BN 256
#define BK 64

#define STG_A(BUF, MH, KT)                                                    \
  { _Pragma("unroll") for (int c_ = 0; c_ < 2; ++c_) {                        \
      const int ri_ = c_ * 64 + srow;                                         \
      const int rg_ = ((ri_ >> 6) << 7) + (MH) * 64 + (ri_ & 63);             \
      const int lg_ = sseg ^ (ri_ & 7);                                       \
      gld_lds16(Ab + (size_t)(s0 + rg_) * K2 + (KT) * BK + (lg_ << 3),        \
                (char*)&sA[BUF][MH][0] + c_ * 8192 + wv * 1024); } }

#define STG_B(BUF, NH, KT)                                                    \
  { _Pragma("unroll") for (int c_ = 0; c_ < 2; ++c_) {                        \
      const int ri_ = c_ * 64 + srow;                                         \
      const int rg_ = ((ri_ >> 5) << 6) + (NH) * 32 + (ri_ & 31);             \
      const int lg_ = sseg ^ (ri_ & 7);                                       \
      gld_lds16(Bw + (size_t)(h0 + rg_) * K2 + (KT) * BK + (lg_ << 3),        \
                (char*)&sB[BUF][NH][0] + c_ * 8192 + wv * 1024); } }

#define RD_A(BUF, MH)                                                         \
    _Pragma("unroll") for (int m_ = 0; m_ < 4; ++m_)                          \
      _Pragma("unroll") for (int k_ = 0; k_ < 2; ++k_)                        \
        af[m_][k_] = *(const short8*)(&sA[BUF][MH][0] + aoff[m_][k_]);

#define RD_B(DST, BUF, NH)                                                    \
    _Pragma("unroll") for (int n_ = 0; n_ < 2; ++n_)                          \
      _Pragma("unroll") for (int k_ = 0; k_ < 2; ++k_)                        \
        DST[n_][k_] = *(const short8*)(&sB[BUF][NH][0] + boff[n_][k_]);

#define MM(MH, NH, BFR)                                                       \
    _Pragma("unroll") for (int k_ = 0; k_ < 2; ++k_)                          \
      _Pragma("unroll") for (int m_ = 0; m_ < 4; ++m_)                        \
        _Pragma("unroll") for (int n_ = 0; n_ < 2; ++n_)                      \
          acc[(MH) * 4 + m_][(NH) * 2 + n_] =                                 \
              __builtin_amdgcn_mfma_f32_16x16x32_bf16(                        \
                  af[m_][k_], BFR[n_][k_],                                    \
                  acc[(MH) * 4 + m_][(NH) * 2 + n_], 0, 0, 0);

#define PH(READS, STAGE, MFMA_, DRAIN)                                        \
  {                                                                           \
    READS                                                                     \
    STAGE                                                                     \
    __builtin_amdgcn_s_barrier();                                             \
    asm volatile("s_waitcnt lgkmcnt(0)" ::: "memory");                        \
    __builtin_amdgcn_sched_barrier(0);                                        \
    __builtin_amdgcn_s_setprio(1);                                            \
    MFMA_                                                                     \
    __builtin_amdgcn_s_setprio(0);                                            \
    DRAIN                                                                     \
    __builtin_amdgcn_s_barrier();                                             \
  }

__global__ __launch_bounds__(512, 2) void gemm_4ph_k(
    const u16* __restrict__ A,      // (B,S,2H) bf16
    const u16* __restrict__ Bw,     // (H,2H) bf16
    const float* __restrict__ hp, const float* __restrict__ vw,
    float* __restrict__ attn) {
  __shared__ __align__(16) u16 sA[2][2][128 * 64];   // [buf][mh][row*64+k] 64KB
  __shared__ __align__(16) u16 sB[2][2][128 * 64];   // [buf][nh][row*64+k] 64KB

  const int tid = threadIdx.x;
  const int lane = tid & 63;
  const int wv = tid >> 6;       // 0..7
  const int wr = wv >> 2;        // 0..1 (M wave-row)
  const int wc = wv & 3;         // 0..3 (N wave-col)
  const int fr = lane & 15;
  const int kgrp = lane >> 4;    // 0..3
  const int srow = wv * 8 + (lane >> 3);  // staging rowidx within 64-row call
  const int sseg = lane & 7;              // staging physical seg

  const int bid = blockIdx.x;             // 512 blocks: ntile*128 + b*4 + mtile
  const int ntile = bid >> 7;             // 0..3
  const int b = (bid >> 2) & 31;
  const int mtile = bid & 3;              // fastest-varying (R1 lesson)
  const int s0 = mtile * BM;
  const int h0 = ntile * BN;

  const u16* Ab = A + (size_t)b * S * K2;

  // thread-invariant frag offsets (u16 units) within a 16KB region
  int aoff[4][2], boff[2][2];
#pragma unroll
  for (int m = 0; m < 4; ++m)
#pragma unroll
    for (int k = 0; k < 2; ++k)
      aoff[m][k] = (wr * 64 + m * 16 + fr) * 64 + ((((k << 2) + kgrp) ^ (fr & 7)) << 3);
#pragma unroll
  for (int n = 0; n < 2; ++n)
#pragma unroll
    for (int k = 0; k < 2; ++k)
      boff[n][k] = (wc * 32 + n * 16 + fr) * 64 + ((((k << 2) + kgrp) ^ (fr & 7)) << 3);

  floatx4 acc[8][4];
#pragma unroll
  for (int i = 0; i < 8; ++i)
#pragma unroll
    for (int j = 0; j < 4; ++j) acc[i][j] = (floatx4){0.f, 0.f, 0.f, 0.f};

  short8 af[4][2], bf0[2][2], bf1[2][2];  // persistent frag registers

  // ---- prologue: buf0<-t0 (4 regions) + buf1<-t1 {A10,B10,B11}; drain to 6
  STG_A(0, 0, 0) STG_B(0, 0, 0) STG_B(0, 1, 0) STG_A(0, 1, 0)
  STG_A(1, 0, 1) STG_B(1, 0, 1) STG_B(1, 1, 1)
  asm volatile("s_waitcnt vmcnt(6)" ::: "memory");   // t0 landed; t1 trio in flight
  __builtin_amdgcn_s_barrier();

  // ---- main loop: iter computes tiles 2it (buf0, Q1-2) and 2it+1 (buf1, Q3-4)
  for (int it = 0; it < 16; ++it) {
    const int t1 = 2 * it + 1, t2 = 2 * it + 2, t3 = 2 * it + 3;
    const bool Lst = (it == 15);
    // Q1 (buf0, mh0): 16 reads; stage sA[1][1]<-t1 (freed prev-iter Q4)
    PH(RD_A(0, 0) RD_B(bf0, 0, 0) RD_B(bf1, 0, 1),
       STG_A(1, 1, t1),
       MM(0, 0, bf0) MM(0, 1, bf1), )
    // Q2 (buf0, mh1): 8 reads; stage sA[0][0]<-t2 (freed Q1); buf1-ready drain
    PH(RD_A(0, 1),
       if (!Lst) { STG_A(0, 0, t2) },
       MM(1, 0, bf0) MM(1, 1, bf1),
       if (Lst) { asm volatile("s_waitcnt vmcnt(0)" ::: "memory"); }
       else     { asm volatile("s_waitcnt vmcnt(2)" ::: "memory"); } )
    // Q3 (buf1, mh0): 16 reads; stage sA[0][1],sB[0][0],sB[0][1]<-t2
    PH(RD_A(1, 0) RD_B(bf0, 1, 0) RD_B(bf1, 1, 1),
       if (!Lst) { STG_A(0, 1, t2) STG_B(0, 0, t2) STG_B(0, 1, t2) },
       MM(0, 0, bf0) MM(0, 1, bf1), )
    // Q4 (buf1, mh1): 8 reads; stage sA[1][0],sB[1][0],sB[1][1]<-t3; buf0-ready drain
    PH(RD_A(1, 1),
       if (!Lst) { STG_A(1, 0, t3) STG_B(1, 0, t3) STG_B(1, 1, t3) },
       MM(1, 0, bf0) MM(1, 1, bf1),
       if (!Lst) { asm volatile("s_waitcnt vmcnt(6)" ::: "memory"); } )
  }

  // ---- epilogue: tanh + v-weighted h-reduction. C/D: col=lane&15, row=(lane>>4)*4+reg
  const int col = fr;
  const int rgrp = lane >> 4;
  float hv[4], vv[4];
#pragma unroll
  for (int nf = 0; nf < 4; ++nf) {
    const int h = h0 + wc * 64 + nf * 16 + col;
    hv[nf] = hp[b * H + h];
    vv[nf] = vw[h];
  }
#pragma unroll
  for (int mf = 0; mf < 8; ++mf) {
#pragma unroll
    for (int r = 0; r < 4; ++r) {
      float part = 0.f;
#pragma unroll
      for (int nf = 0; nf < 4; ++nf) part += tanh_fast(acc[mf][nf][r] + hv[nf]) * vv[nf];
      part += __shfl_xor(part, 1);
      part += __shfl_xor(part, 2);
      part += __shfl_xor(part, 4);
      part += __shfl_xor(part, 8);   // sum over 16 col-lanes; preserves rgrp
      if (col == 0)
        atomicAdd(&attn[b * S + s0 + wr * 128 + mf * 16 + rgrp * 4 + r], part);
    }
  }
}

__global__ void softmax_k(const float* __restrict__ attn, float* __restrict__ out) {
  __shared__ float red[8];
  const int b = blockIdx.x;
  const int tid = threadIdx.x;
  const float* row = attn + b * S;
  float v[4];
#pragma unroll
  for (int i = 0; i < 4; i++) v[i] = row[tid + i * 256];
  float m = fmaxf(fmaxf(v[0], v[1]), fmaxf(v[2], v[3]));
#pragma unroll
  for (int off = 32; off; off >>= 1) m = fmaxf(m, __shfl_xor(m, off));
  if ((tid & 63) == 0) red[tid >> 6] = m;
  __syncthreads();
  m = fmaxf(fmaxf(red[0], red[1]), fmaxf(red[2], red[3]));
  float e[4], sum = 0.f;
#pragma unroll
  for (int i = 0; i < 4; i++) { e[i] = __expf(v[i] - m); sum += e[i]; }
#pragma unroll
  for (int off = 32; off; off >>= 1) sum += __shfl_xor(sum, off);
  __syncthreads();
  if ((tid & 63) == 0) red[4 + (tid >> 6)] = sum;
  __syncthreads();
  sum = red[4] + red[5] + red[6] + red[7];
  const float inv = 1.0f / sum;
#pragma unroll
  for (int i = 0; i < 4; i++) out[b * S + tid + i * 256] = e[i] * inv;
}

extern "C" void kernel_launch(void* const* d_in, const int* in_sizes, int n_in,
                              void* d_out, int out_size, void* d_ws, size_t ws_size,
                              hipStream_t stream) {
  const float* enc    = (const float*)d_in[0];  // (S,B,2H)
  const float* hidden = (const float*)d_in[1];  // (B,H)
  // d_in[2] = cell — unused by the reference
  const float* W_attn = (const float*)d_in[3];  // (H,3H)
  const float* b_attn = (const float*)d_in[4];  // (H)
  const float* v_w    = (const float*)d_in[5];  // (H)
  float* out = (float*)d_out;                   // (B,S)

  char* ws = (char*)d_ws;
  float* attn = (float*)ws;                                  // 128 KiB
  float* hp   = (float*)(ws + 131072);                       // 128 KiB
  u16* Web    = (u16*)(ws + 262144);                         // 4 MiB
  u16* encb   = (u16*)(ws + 4456448);                        // 128 MiB (B,S,2H) bf16

  hipMemsetAsync(attn, 0, B * S * sizeof(float), stream);    // ws is 0xAA-poisoned each call
  conv_we_k<<<H, 256, 0, stream>>>(W_attn, Web);
  hproj_k<<<256, 256, 0, stream>>>(hidden, W_attn, b_attn, hp);
  conv_enc_k<<<S * B, 256, 0, stream>>>(enc, encb);
  gemm_4ph_k<<<512, 512, 0, stream>>>(encb, Web, hp, v_w, attn);
  softmax_k<<<B, 256, 0, stream>>>(attn, out);
}

// Round 8
// 548.549 us; speedup vs baseline: 1.0174x; 1.0174x over previous
//
#include <hip/hip_runtime.h>
#include <hip/hip_bf16.h>

#define H 1024
#define S 1024
#define B 32
#define K2 2048  // 2*H

typedef unsigned short u16;
typedef __attribute__((ext_vector_type(8))) short short8;     // 8 bf16 (4 VGPRs) — MFMA A/B frag
typedef __attribute__((ext_vector_type(8))) unsigned short u16x8;
typedef __attribute__((ext_vector_type(4))) float floatx4;    // MFMA C/D frag

__device__ __forceinline__ u16 f2bf(float f) {
  unsigned u = __float_as_uint(f);
  u += 0x7FFFu + ((u >> 16) & 1u);   // RNE to bf16
  return (u16)(u >> 16);
}

// async global->LDS, 16B per lane; global addr is PER-LANE, LDS dest = wave-uniform base + lane*16
__device__ __forceinline__ void gld_lds16(const void* g, void* l) {
  __builtin_amdgcn_global_load_lds(
      (const __attribute__((address_space(1))) unsigned int*)g,
      (__attribute__((address_space(3))) unsigned int*)l, 16, 0, 0);
}

// fast tanh: 1 - 2/(e^{2x}+1). Exact +-1 asymptotes, ~6 VALU ops, |err| ~ 1e-7.
__device__ __forceinline__ float tanh_fast(float x) {
  float t = __expf(2.0f * x);
  return 1.0f - 2.0f / (t + 1.0f);
}

// W_attn (H,3H) fp32 -> W_e bf16 (H,2H)
__global__ void conv_we_k(const float* __restrict__ W, u16* __restrict__ dst) {
  const int h = blockIdx.x;
  const int t = threadIdx.x * 8;
  const float* sp = W + (size_t)h * 3072 + H + t;
  u16* dp = dst + (size_t)h * K2 + t;
  floatx4 x = *(const floatx4*)sp;
  floatx4 y = *(const floatx4*)(sp + 4);
  u16x8 o;
  o[0] = f2bf(x[0]); o[1] = f2bf(x[1]); o[2] = f2bf(x[2]); o[3] = f2bf(x[3]);
  o[4] = f2bf(y[0]); o[5] = f2bf(y[1]); o[6] = f2bf(y[2]); o[7] = f2bf(y[3]);
  *(u16x8*)dp = o;
}

// enc (S,B,2H) fp32 -> encb (B,S,2H) bf16. Pure BW pass (~384MB traffic).
__global__ void conv_enc_k(const float* __restrict__ enc, u16* __restrict__ dst) {
  const int sb = blockIdx.x;          // s*B + b
  const int s = sb >> 5;
  const int b = sb & 31;
  const int t = threadIdx.x * 8;
  const float* sp = enc + (size_t)sb * K2 + t;
  u16* dp = dst + ((size_t)b * S + s) * K2 + t;
  floatx4 x = *(const floatx4*)sp;
  floatx4 y = *(const floatx4*)(sp + 4);
  u16x8 o;
  o[0] = f2bf(x[0]); o[1] = f2bf(x[1]); o[2] = f2bf(x[2]); o[3] = f2bf(x[3]);
  o[4] = f2bf(y[0]); o[5] = f2bf(y[1]); o[6] = f2bf(y[2]); o[7] = f2bf(y[3]);
  *(u16x8*)dp = o;
}

// h_proj[b,h] = hidden[b,:] . W_attn[h, 0:H] + b_attn[h]   (fp32 exact path)
__global__ void hproj_k(const float* __restrict__ hidden, const float* __restrict__ W,
                        const float* __restrict__ b_attn, float* __restrict__ hp) {
  const int lane = threadIdx.x & 63;
  const int h = (blockIdx.x * blockDim.x + threadIdx.x) >> 6;
  float wr[16];
#pragma unroll
  for (int i = 0; i < 16; i++) wr[i] = W[(size_t)h * 3072 + lane + i * 64];
  for (int b = 0; b < B; b++) {
    float d = 0.f;
#pragma unroll
    for (int i = 0; i < 16; i++) d = fmaf(wr[i], hidden[b * H + lane + i * 64], d);
#pragma unroll
    for (int off = 32; off; off >>= 1) d += __shfl_xor(d, off);
    if (lane == 0) hp[b * H + h] = d + b_attn[h];
  }
}

// ===================== 256x256 8-phase GEMM (T2+T3+T4+T5) =====================
// 8 waves (2M x 4N), per-wave output 128x64, BK=64, 32 K-tiles, 2 tiles/iter.
// LDS 128KB: sA/sB x 2 bufs x 2 regions x (128 rows x 64 bf16).
// R6 zig-zag (measured best: gemm 156.6us): per-buffer phase order
// (0,0)->(0,1)->(1,1)->(1,0), A-frags reused across adjacent pairs, bf0
// persists P1->P4. 48 ds_read_b128/iter (12/4/8/0).
// ROUND-8 CHANGE (single mechanism): remove the blunt `s_waitcnt lgkmcnt(0)`
// phase pin. The compiler emits fine-grained counted lgkmcnt(N) before each
// dependent MFMA (m97 asm evidence), so the first MFMA starts when only its
// own 2 frags have landed instead of after the wave's full 12-read burst has
// been served by the contended LDS pipe (8 waves x 12 reads ~ 1150cy queue).
// Reads ordered bf-first so first-use order pipelines (first MFMA consumes
// reads #1 and #5). Stage rotation / vmcnt ledger / barriers / setprio are
// byte-identical to R6:
//   sA[1][1]:P1<-t1  sA[0][0]:P2<-t2  sB[0][0]:P3<-t2  sB[0][1]:P4<-t2
//   sA[0][1]:P5<-t2  sA[1][0]:P6<-t3  sB[1][0]:P7<-t3  sB[1][1]:P8<-t3
// Drains: vmcnt(6) at P4-end & P8-end (keep 3 newest stage units in flight);
// last iter P4 drains to 0.
#define BM 256
#define BN 256
#define BK 64

#define STG_A(BUF, MH, KT)                                                    \
  { _Pragma("unroll") for (int c_ = 0; c_ < 2; ++c_) {                        \
      const int ri_ = c_ * 64 + srow;                                         \
      const int rg_ = ((ri_ >> 6) << 7) + (MH) * 64 + (ri_ & 63);             \
      const int lg_ = sseg ^ (ri_ & 7);                                       \
      gld_lds16(Ab + (size_t)(s0 + rg_) * K2 + (KT) * BK + (lg_ << 3),        \
                (char*)&sA[BUF][MH][0] + c_ * 8192 + wv * 1024); } }

#define STG_B(BUF, NH, KT)                                                    \
  { _Pragma("unroll") for (int c_ = 0; c_ < 2; ++c_) {                        \
      const int ri_ = c_ * 64 + srow;                                         \
      const int rg_ = ((ri_ >> 5) << 6) + (NH) * 32 + (ri_ & 31);             \
      const int lg_ = sseg ^ (ri_ & 7);                                       \
      gld_lds16(Bw + (size_t)(h0 + rg_) * K2 + (KT) * BK + (lg_ << 3),        \
                (char*)&sB[BUF][NH][0] + c_ * 8192 + wv * 1024); } }

#define RD_A(BUF, MH)                                                         \
    _Pragma("unroll") for (int m_ = 0; m_ < 4; ++m_)                          \
      _Pragma("unroll") for (int k_ = 0; k_ < 2; ++k_)                        \
        af[m_][k_] = *(const short8*)(&sA[BUF][MH][0] + aoff[m_][k_]);

#define RD_B(DST, BUF, NH)                                                    \
    _Pragma("unroll") for (int n_ = 0; n_ < 2; ++n_)                          \
      _Pragma("unroll") for (int k_ = 0; k_ < 2; ++k_)                        \
        DST[n_][k_] = *(const short8*)(&sB[BUF][NH][0] + boff[n_][k_]);

#define MM(MH, NH, BFR)                                                       \
    _Pragma("unroll") for (int k_ = 0; k_ < 2; ++k_)                          \
      _Pragma("unroll") for (int m_ = 0; m_ < 4; ++m_)                        \
        _Pragma("unroll") for (int n_ = 0; n_ < 2; ++n_)                      \
          acc[(MH) * 4 + m_][(NH) * 2 + n_] =                                 \
              __builtin_amdgcn_mfma_f32_16x16x32_bf16(                        \
                  af[m_][k_], BFR[n_][k_],                                    \
                  acc[(MH) * 4 + m_][(NH) * 2 + n_], 0, 0, 0);

// NOTE: no explicit lgkmcnt pin — compiler inserts fine-grained counted
// waits per MFMA data dependence (staged consumption).
#define PH(READS, STAGE, MFMA_, DRAIN)                                        \
  {                                                                           \
    READS                                                                     \
    STAGE                                                                     \
    __builtin_amdgcn_s_barrier();                                             \
    __builtin_amdgcn_s_setprio(1);                                            \
    MFMA_                                                                     \
    __builtin_amdgcn_s_setprio(0);                                            \
    DRAIN                                                                     \
    __builtin_amdgcn_s_barrier();                                             \
  }

__global__ __launch_bounds__(512, 2) void gemm_8ph_k(
    const u16* __restrict__ A,      // (B,S,2H) bf16
    const u16* __restrict__ Bw,     // (H,2H) bf16
    const float* __restrict__ hp, const float* __restrict__ vw,
    float* __restrict__ attn) {
  __shared__ __align__(16) u16 sA[2][2][128 * 64];   // [buf][mh][row*64+k] 64KB
  __shared__ __align__(16) u16 sB[2][2][128 * 64];   // [buf][nh][row*64+k] 64KB

  const int tid = threadIdx.x;
  const int lane = tid & 63;
  const int wv = tid >> 6;       // 0..7
  const int wr = wv >> 2;        // 0..1 (M wave-row)
  const int wc = wv & 3;         // 0..3 (N wave-col)
  const int fr = lane & 15;
  const int kgrp = lane >> 4;    // 0..3
  const int srow = wv * 8 + (lane >> 3);  // staging rowidx within 64-row call
  const int sseg = lane & 7;              // staging physical seg

  const int bid = blockIdx.x;             // 512 blocks: ntile*128 + b*4 + mtile
  const int ntile = bid >> 7;             // 0..3
  const int b = (bid >> 2) & 31;
  const int mtile = bid & 3;              // fastest-varying (R1 lesson)
  const int s0 = mtile * BM;
  const int h0 = ntile * BN;

  const u16* Ab = A + (size_t)b * S * K2;

  // thread-invariant frag offsets (u16 units) within a 16KB region
  int aoff[4][2], boff[2][2];
#pragma unroll
  for (int m = 0; m < 4; ++m)
#pragma unroll
    for (int k = 0; k < 2; ++k)
      aoff[m][k] = (wr * 64 + m * 16 + fr) * 64 + ((((k << 2) + kgrp) ^ (fr & 7)) << 3);
#pragma unroll
  for (int n = 0; n < 2; ++n)
#pragma unroll
    for (int k = 0; k < 2; ++k)
      boff[n][k] = (wc * 32 + n * 16 + fr) * 64 + ((((k << 2) + kgrp) ^ (fr & 7)) << 3);

  floatx4 acc[8][4];
#pragma unroll
  for (int i = 0; i < 8; ++i)
#pragma unroll
    for (int j = 0; j < 4; ++j) acc[i][j] = (floatx4){0.f, 0.f, 0.f, 0.f};

  short8 af[4][2], bf0[2][2], bf1[2][2];  // persistent frag registers

  // ---- prologue: t0 all 4 regions + t1 {A10,B10,B11}; drain to 3 in flight
  STG_A(0, 0, 0) STG_B(0, 0, 0) STG_B(0, 1, 0) STG_A(0, 1, 0)
  STG_A(1, 0, 1) STG_B(1, 0, 1) STG_B(1, 1, 1)
  asm volatile("s_waitcnt vmcnt(6)" ::: "memory");   // t0 landed; t1 trio in flight
  __builtin_amdgcn_s_barrier();

  // ---- main loop: iter computes tiles 2it (buf0, P1-4) and 2it+1 (buf1, P5-8)
  for (int it = 0; it < 16; ++it) {
    const int t1 = 2 * it + 1, t2 = 2 * it + 2, t3 = 2 * it + 3;
    const bool Lst = (it == 15);
    // P1 (0,0): reads bf0<-B[0][0] FIRST, then af<-A[0][0]; stage A[1][1]<-t1
    PH(RD_B(bf0, 0, 0) RD_A(0, 0), STG_A(1, 1, t1), MM(0, 0, bf0), )
    // P2 (0,1): read bf1<-B[0][1]; stage A[0][0]<-t2
    PH(RD_B(bf1, 0, 1), if (!Lst) { STG_A(0, 0, t2) }, MM(0, 1, bf1), )
    // P3 (1,1): read af<-A[0][1]; stage B[0][0]<-t2
    PH(RD_A(0, 1), if (!Lst) { STG_B(0, 0, t2) }, MM(1, 1, bf1), )
    // P4 (1,0): no reads (af, bf0 persisted); stage B[0][1]<-t2; K-tile drain
    PH(, if (!Lst) { STG_B(0, 1, t2) }, MM(1, 0, bf0),
       if (Lst) { asm volatile("s_waitcnt vmcnt(0)" ::: "memory"); }
       else     { asm volatile("s_waitcnt vmcnt(6)" ::: "memory"); } )
    // P5 (0,0): reads bf0<-B[1][0] FIRST, then af<-A[1][0]; stage A[0][1]<-t2
    PH(RD_B(bf0, 1, 0) RD_A(1, 0), if (!Lst) { STG_A(0, 1, t2) }, MM(0, 0, bf0), )
    // P6 (0,1): read bf1<-B[1][1]; stage A[1][0]<-t3
    PH(RD_B(bf1, 1, 1), if (!Lst) { STG_A(1, 0, t3) }, MM(0, 1, bf1), )
    // P7 (1,1): read af<-A[1][1]; stage B[1][0]<-t3
    PH(RD_A(1, 1), if (!Lst) { STG_B(1, 0, t3) }, MM(1, 1, bf1), )
    // P8 (1,0): no reads; stage B[1][1]<-t3; K-tile drain
    PH(, if (!Lst) { STG_B(1, 1, t3) }, MM(1, 0, bf0),
       if (!Lst) { asm volatile("s_waitcnt vmcnt(6)" ::: "memory"); } )
  }

  // ---- epilogue: tanh + v-weighted h-reduction. C/D: col=lane&15, row=(lane>>4)*4+reg
  const int col = fr;
  const int rgrp = lane >> 4;
  float hv[4], vv[4];
#pragma unroll
  for (int nf = 0; nf < 4; ++nf) {
    const int h = h0 + wc * 64 + nf * 16 + col;
    hv[nf] = hp[b * H + h];
    vv[nf] = vw[h];
  }
#pragma unroll
  for (int mf = 0; mf < 8; ++mf) {
#pragma unroll
    for (int r = 0; r < 4; ++r) {
      float part = 0.f;
#pragma unroll
      for (int nf = 0; nf < 4; ++nf) part += tanh_fast(acc[mf][nf][r] + hv[nf]) * vv[nf];
      part += __shfl_xor(part, 1);
      part += __shfl_xor(part, 2);
      part += __shfl_xor(part, 4);
      part += __shfl_xor(part, 8);   // sum over 16 col-lanes; preserves rgrp
      if (col == 0)
        atomicAdd(&attn[b * S + s0 + wr * 128 + mf * 16 + rgrp * 4 + r], part);
    }
  }
}

__global__ void softmax_k(const float* __restrict__ attn, float* __restrict__ out) {
  __shared__ float red[8];
  const int b = blockIdx.x;
  const int tid = threadIdx.x;
  const float* row = attn + b * S;
  float v[4];
#pragma unroll
  for (int i = 0; i < 4; i++) v[i] = row[tid + i * 256];
  float m = fmaxf(fmaxf(v[0], v[1]), fmaxf(v[2], v[3]));
#pragma unroll
  for (int off = 32; off; off >>= 1) m = fmaxf(m, __shfl_xor(m, off));
  if ((tid & 63) == 0) red[tid >> 6] = m;
  __syncthreads();
  m = fmaxf(fmaxf(red[0], red[1]), fmaxf(red[2], red[3]));
  float e[4], sum = 0.f;
#pragma unroll
  for (int i = 0; i < 4; i++) { e[i] = __expf(v[i] - m); sum += e[i]; }
#pragma unroll
  for (int off = 32; off; off >>= 1) sum += __shfl_xor(sum, off);
  __syncthreads();
  if ((tid & 63) == 0) red[4 + (tid >> 6)] = sum;
  __syncthreads();
  sum = red[4] + red[5] + red[6] + red[7];
  const float inv = 1.0f / sum;
#pragma unroll
  for (int i = 0; i < 4; i++) out[b * S + tid + i * 256] = e[i] * inv;
}

extern "C" void kernel_launch(void* const* d_in, const int* in_sizes, int n_in,
                              void* d_out, int out_size, void* d_ws, size_t ws_size,
                              hipStream_t stream) {
  const float* enc    = (const float*)d_in[0];  // (S,B,2H)
  const float* hidden = (const float*)d_in[1];  // (B,H)
  // d_in[2] = cell — unused by the reference
  const float* W_attn = (const float*)d_in[3];  // (H,3H)
  const float* b_attn = (const float*)d_in[4];  // (H)
  const float* v_w    = (const float*)d_in[5];  // (H)
  float* out = (float*)d_out;                   // (B,S)

  char* ws = (char*)d_ws;
  float* attn = (float*)ws;                                  // 128 KiB
  float* hp   = (float*)(ws + 131072);                       // 128 KiB
  u16* Web    = (u16*)(ws + 262144);                         // 4 MiB
  u16* encb   = (u16*)(ws + 4456448);                        // 128 MiB (B,S,2H) bf16

  hipMemsetAsync(attn, 0, B * S * sizeof(float), stream);    // ws is 0xAA-poisoned each call
  conv_we_k<<<H, 256, 0, stream>>>(W_attn, Web);
  hproj_k<<<256, 256, 0, stream>>>(hidden, W_attn, b_attn, hp);
  conv_enc_k<<<S * B, 256, 0, stream>>>(enc, encb);
  gemm_8ph_k<<<512, 512, 0, stream>>>(encb, Web, hp, v_w, attn);
  softmax_k<<<B, 256, 0, stream>>>(attn, out);
}

// Round 9
// 544.535 us; speedup vs baseline: 1.0249x; 1.0074x over previous
//
#include <hip/hip_runtime.h>
#include <hip/hip_bf16.h>

#define H 1024
#define S 1024
#define B 32
#define K2 2048  // 2*H

typedef unsigned short u16;
typedef __attribute__((ext_vector_type(8))) short short8;     // 8 bf16 (4 VGPRs) — MFMA A/B frag
typedef __attribute__((ext_vector_type(8))) unsigned short u16x8;
typedef __attribute__((ext_vector_type(4))) float floatx4;    // MFMA C/D frag

__device__ __forceinline__ u16 f2bf(float f) {
  unsigned u = __float_as_uint(f);
  u += 0x7FFFu + ((u >> 16) & 1u);   // RNE to bf16
  return (u16)(u >> 16);
}

// async global->LDS, 16B per lane; global addr is PER-LANE, LDS dest = wave-uniform base + lane*16
__device__ __forceinline__ void gld_lds16(const void* g, void* l) {
  __builtin_amdgcn_global_load_lds(
      (const __attribute__((address_space(1))) unsigned int*)g,
      (__attribute__((address_space(3))) unsigned int*)l, 16, 0, 0);
}

// fast tanh: 1 - 2/(e^{2x}+1). Exact +-1 asymptotes, ~6 VALU ops, |err| ~ 1e-7.
__device__ __forceinline__ float tanh_fast(float x) {
  float t = __expf(2.0f * x);
  return 1.0f - 2.0f / (t + 1.0f);
}

// W_attn (H,3H) fp32 -> W_e bf16 (H,2H)
__global__ void conv_we_k(const float* __restrict__ W, u16* __restrict__ dst) {
  const int h = blockIdx.x;
  const int t = threadIdx.x * 8;
  const float* sp = W + (size_t)h * 3072 + H + t;
  u16* dp = dst + (size_t)h * K2 + t;
  floatx4 x = *(const floatx4*)sp;
  floatx4 y = *(const floatx4*)(sp + 4);
  u16x8 o;
  o[0] = f2bf(x[0]); o[1] = f2bf(x[1]); o[2] = f2bf(x[2]); o[3] = f2bf(x[3]);
  o[4] = f2bf(y[0]); o[5] = f2bf(y[1]); o[6] = f2bf(y[2]); o[7] = f2bf(y[3]);
  *(u16x8*)dp = o;
}

// enc (S,B,2H) fp32 -> encb (B,S,2H) bf16. Pure BW pass (~384MB traffic).
__global__ void conv_enc_k(const float* __restrict__ enc, u16* __restrict__ dst) {
  const int sb = blockIdx.x;          // s*B + b
  const int s = sb >> 5;
  const int b = sb & 31;
  const int t = threadIdx.x * 8;
  const float* sp = enc + (size_t)sb * K2 + t;
  u16* dp = dst + ((size_t)b * S + s) * K2 + t;
  floatx4 x = *(const floatx4*)sp;
  floatx4 y = *(const floatx4*)(sp + 4);
  u16x8 o;
  o[0] = f2bf(x[0]); o[1] = f2bf(x[1]); o[2] = f2bf(x[2]); o[3] = f2bf(x[3]);
  o[4] = f2bf(y[0]); o[5] = f2bf(y[1]); o[6] = f2bf(y[2]); o[7] = f2bf(y[3]);
  *(u16x8*)dp = o;
}

// h_proj[b,h] = hidden[b,:] . W_attn[h, 0:H] + b_attn[h]   (fp32 exact path)
__global__ void hproj_k(const float* __restrict__ hidden, const float* __restrict__ W,
                        const float* __restrict__ b_attn, float* __restrict__ hp) {
  const int lane = threadIdx.x & 63;
  const int h = (blockIdx.x * blockDim.x + threadIdx.x) >> 6;
  float wr[16];
#pragma unroll
  for (int i = 0; i < 16; i++) wr[i] = W[(size_t)h * 3072 + lane + i * 64];
  for (int b = 0; b < B; b++) {
    float d = 0.f;
#pragma unroll
    for (int i = 0; i < 16; i++) d = fmaf(wr[i], hidden[b * H + lane + i * 64], d);
#pragma unroll
    for (int off = 32; off; off >>= 1) d += __shfl_xor(d, off);
    if (lane == 0) hp[b * H + h] = d + b_attn[h];
  }
}

// ===================== 256x256 8-phase GEMM (T2+T3+T4+T5) =====================
// 8 waves (2M x 4N), per-wave output 128x64, BK=64, 32 K-tiles, 2 tiles/iter.
// LDS 128KB: sA/sB x 2 bufs x 2 regions x (128 rows x 64 bf16).
// R6 zig-zag read/stage pattern (best measured: 156.6us, MfmaUtil 37.8):
// (0,0)->(0,1)->(1,1)->(1,0) per buffer, bf0 persists P1->P4, 48 reads/iter.
// ROUND-9 CHANGE (single mechanism): SINGLE barrier per phase.
//   phase = READS; STAGE; lgkmcnt(0); [vmcnt drain]; s_barrier; MFMA
// Safety: the explicit lgkmcnt(0) BEFORE the barrier drains every wave's LDS
// reads at arrival, so a stage issued after the barrier cannot race an
// in-flight read. Rotation check (region: last-read phase -> stage phase):
//   A[1][1]: P7 -> next P1   A[0][0]: P1 -> P2   B[0][0]: P1 -> P3
//   B[0][1]: P2 -> P4        A[0][1]: P3 -> P5   A[1][0]: P5 -> P6
//   B[1][0]: P5 -> P7        B[1][1]: P6 -> P8      (all >=1 barrier apart)
// vmcnt ledger identical to R6: drains to 6 at P4/P8 (now placed BEFORE the
// barrier -> staged data visible to the next phase's readers), last-iter P4
// drains to 0. Prologue leaves exactly the steady-state 6 in flight.
// Win mechanisms: 8 barriers/iter instead of 16 (256->128 rendezvous per
// K-loop at 1 block/CU), and a wave finishing MFMA early flows into the next
// phase's reads/stage while slower waves still run MFMA (cross-wave
// read||MFMA overlap that the 2-barrier lockstep forbids).
#define BM 256
#define BN 256
#define BK 64

#define STG_A(BUF, MH, KT)                                                    \
  { _Pragma("unroll") for (int c_ = 0; c_ < 2; ++c_) {                        \
      const int ri_ = c_ * 64 + srow;                                         \
      const int rg_ = ((ri_ >> 6) << 7) + (MH) * 64 + (ri_ & 63);             \
      const int lg_ = sseg ^ (ri_ & 7);                                       \
      gld_lds16(Ab + (size_t)(s0 + rg_) * K2 + (KT) * BK + (lg_ << 3),        \
                (char*)&sA[BUF][MH][0] + c_ * 8192 + wv * 1024); } }

#define STG_B(BUF, NH, KT)                                                    \
  { _Pragma("unroll") for (int c_ = 0; c_ < 2; ++c_) {                        \
      const int ri_ = c_ * 64 + srow;                                         \
      const int rg_ = ((ri_ >> 5) << 6) + (NH) * 32 + (ri_ & 31);             \
      const int lg_ = sseg ^ (ri_ & 7);                                       \
      gld_lds16(Bw + (size_t)(h0 + rg_) * K2 + (KT) * BK + (lg_ << 3),        \
                (char*)&sB[BUF][NH][0] + c_ * 8192 + wv * 1024); } }

#define RD_A(BUF, MH)                                                         \
    _Pragma("unroll") for (int m_ = 0; m_ < 4; ++m_)                          \
      _Pragma("unroll") for (int k_ = 0; k_ < 2; ++k_)                        \
        af[m_][k_] = *(const short8*)(&sA[BUF][MH][0] + aoff[m_][k_]);

#define RD_B(DST, BUF, NH)                                                    \
    _Pragma("unroll") for (int n_ = 0; n_ < 2; ++n_)                          \
      _Pragma("unroll") for (int k_ = 0; k_ < 2; ++k_)                        \
        DST[n_][k_] = *(const short8*)(&sB[BUF][NH][0] + boff[n_][k_]);

#define MM(MH, NH, BFR)                                                       \
    _Pragma("unroll") for (int k_ = 0; k_ < 2; ++k_)                          \
      _Pragma("unroll") for (int m_ = 0; m_ < 4; ++m_)                        \
        _Pragma("unroll") for (int n_ = 0; n_ < 2; ++n_)                      \
          acc[(MH) * 4 + m_][(NH) * 2 + n_] =                                 \
              __builtin_amdgcn_mfma_f32_16x16x32_bf16(                        \
                  af[m_][k_], BFR[n_][k_],                                    \
                  acc[(MH) * 4 + m_][(NH) * 2 + n_], 0, 0, 0);

// Single-barrier phase. lgkmcnt(0) drains this wave's LDS reads BEFORE the
// barrier (cross-wave stage-write safety); vmcnt drain also before the
// barrier so newly-landed tiles are visible to the next phase's readers.
// sched_barrier(0) pins MFMA below the barrier (rule 18).
#define PH(READS, STAGE, MFMA_, DRAIN)                                        \
  {                                                                           \
    READS                                                                     \
    STAGE                                                                     \
    asm volatile("s_waitcnt lgkmcnt(0)" ::: "memory");                        \
    DRAIN                                                                     \
    __builtin_amdgcn_s_barrier();                                             \
    __builtin_amdgcn_sched_barrier(0);                                        \
    __builtin_amdgcn_s_setprio(1);                                            \
    MFMA_                                                                     \
    __builtin_amdgcn_s_setprio(0);                                            \
  }

__global__ __launch_bounds__(512, 2) void gemm_8ph_k(
    const u16* __restrict__ A,      // (B,S,2H) bf16
    const u16* __restrict__ Bw,     // (H,2H) bf16
    const float* __restrict__ hp, const float* __restrict__ vw,
    float* __restrict__ attn) {
  __shared__ __align__(16) u16 sA[2][2][128 * 64];   // [buf][mh][row*64+k] 64KB
  __shared__ __align__(16) u16 sB[2][2][128 * 64];   // [buf][nh][row*64+k] 64KB

  const int tid = threadIdx.x;
  const int lane = tid & 63;
  const int wv = tid >> 6;       // 0..7
  const int wr = wv >> 2;        // 0..1 (M wave-row)
  const int wc = wv & 3;         // 0..3 (N wave-col)
  const int fr = lane & 15;
  const int kgrp = lane >> 4;    // 0..3
  const int srow = wv * 8 + (lane >> 3);  // staging rowidx within 64-row call
  const int sseg = lane & 7;              // staging physical seg

  const int bid = blockIdx.x;             // 512 blocks: ntile*128 + b*4 + mtile
  const int ntile = bid >> 7;             // 0..3
  const int b = (bid >> 2) & 31;
  const int mtile = bid & 3;              // fastest-varying (R1 lesson)
  const int s0 = mtile * BM;
  const int h0 = ntile * BN;

  const u16* Ab = A + (size_t)b * S * K2;

  // thread-invariant frag offsets (u16 units) within a 16KB region
  int aoff[4][2], boff[2][2];
#pragma unroll
  for (int m = 0; m < 4; ++m)
#pragma unroll
    for (int k = 0; k < 2; ++k)
      aoff[m][k] = (wr * 64 + m * 16 + fr) * 64 + ((((k << 2) + kgrp) ^ (fr & 7)) << 3);
#pragma unroll
  for (int n = 0; n < 2; ++n)
#pragma unroll
    for (int k = 0; k < 2; ++k)
      boff[n][k] = (wc * 32 + n * 16 + fr) * 64 + ((((k << 2) + kgrp) ^ (fr & 7)) << 3);

  floatx4 acc[8][4];
#pragma unroll
  for (int i = 0; i < 8; ++i)
#pragma unroll
    for (int j = 0; j < 4; ++j) acc[i][j] = (floatx4){0.f, 0.f, 0.f, 0.f};

  short8 af[4][2], bf0[2][2], bf1[2][2];  // persistent frag registers

  // ---- prologue: t0 all 4 regions + t1 {A10,B10,B11}; drain to 3 units in flight
  STG_A(0, 0, 0) STG_B(0, 0, 0) STG_B(0, 1, 0) STG_A(0, 1, 0)
  STG_A(1, 0, 1) STG_B(1, 0, 1) STG_B(1, 1, 1)
  asm volatile("s_waitcnt vmcnt(6)" ::: "memory");   // t0 landed; t1 trio in flight
  __builtin_amdgcn_s_barrier();

  // ---- main loop: iter computes tiles 2it (buf0, P1-4) and 2it+1 (buf1, P5-8)
  for (int it = 0; it < 16; ++it) {
    const int t1 = 2 * it + 1, t2 = 2 * it + 2, t3 = 2 * it + 3;
    const bool Lst = (it == 15);
    // P1 (0,0): reads bf0<-B[0][0], af<-A[0][0]; stage A[1][1]<-t1
    PH(RD_B(bf0, 0, 0) RD_A(0, 0), STG_A(1, 1, t1), MM(0, 0, bf0), )
    // P2 (0,1): read bf1<-B[0][1]; stage A[0][0]<-t2
    PH(RD_B(bf1, 0, 1), if (!Lst) { STG_A(0, 0, t2) }, MM(0, 1, bf1), )
    // P3 (1,1): read af<-A[0][1]; stage B[0][0]<-t2
    PH(RD_A(0, 1), if (!Lst) { STG_B(0, 0, t2) }, MM(1, 1, bf1), )
    // P4 (1,0): no reads (af, bf0 persisted); stage B[0][1]<-t2; K-tile drain
    PH(, if (!Lst) { STG_B(0, 1, t2) }, MM(1, 0, bf0),
       if (Lst) { asm volatile("s_waitcnt vmcnt(0)" ::: "memory"); }
       else     { asm volatile("s_waitcnt vmcnt(6)" ::: "memory"); } )
    // P5 (0,0): reads bf0<-B[1][0], af<-A[1][0]; stage A[0][1]<-t2
    PH(RD_B(bf0, 1, 0) RD_A(1, 0), if (!Lst) { STG_A(0, 1, t2) }, MM(0, 0, bf0), )
    // P6 (0,1): read bf1<-B[1][1]; stage A[1][0]<-t3
    PH(RD_B(bf1, 1, 1), if (!Lst) { STG_A(1, 0, t3) }, MM(0, 1, bf1), )
    // P7 (1,1): read af<-A[1][1]; stage B[1][0]<-t3
    PH(RD_A(1, 1), if (!Lst) { STG_B(1, 0, t3) }, MM(1, 1, bf1), )
    // P8 (1,0): no reads; stage B[1][1]<-t3; K-tile drain
    PH(, if (!Lst) { STG_B(1, 1, t3) }, MM(1, 0, bf0),
       if (!Lst) { asm volatile("s_waitcnt vmcnt(6)" ::: "memory"); } )
  }

  // ---- epilogue: tanh + v-weighted h-reduction. C/D: col=lane&15, row=(lane>>4)*4+reg
  const int col = fr;
  const int rgrp = lane >> 4;
  float hv[4], vv[4];
#pragma unroll
  for (int nf = 0; nf < 4; ++nf) {
    const int h = h0 + wc * 64 + nf * 16 + col;
    hv[nf] = hp[b * H + h];
    vv[nf] = vw[h];
  }
#pragma unroll
  for (int mf = 0; mf < 8; ++mf) {
#pragma unroll
    for (int r = 0; r < 4; ++r) {
      float part = 0.f;
#pragma unroll
      for (int nf = 0; nf < 4; ++nf) part += tanh_fast(acc[mf][nf][r] + hv[nf]) * vv[nf];
      part += __shfl_xor(part, 1);
      part += __shfl_xor(part, 2);
      part += __shfl_xor(part, 4);
      part += __shfl_xor(part, 8);   // sum over 16 col-lanes; preserves rgrp
      if (col == 0)
        atomicAdd(&attn[b * S + s0 + wr * 128 + mf * 16 + rgrp * 4 + r], part);
    }
  }
}

__global__ void softmax_k(const float* __restrict__ attn, float* __restrict__ out) {
  __shared__ float red[8];
  const int b = blockIdx.x;
  const int tid = threadIdx.x;
  const float* row = attn + b * S;
  float v[4];
#pragma unroll
  for (int i = 0; i < 4; i++) v[i] = row[tid + i * 256];
  float m = fmaxf(fmaxf(v[0], v[1]), fmaxf(v[2], v[3]));
#pragma unroll
  for (int off = 32; off; off >>= 1) m = fmaxf(m, __shfl_xor(m, off));
  if ((tid & 63) == 0) red[tid >> 6] = m;
  __syncthreads();
  m = fmaxf(fmaxf(red[0], red[1]), fmaxf(red[2], red[3]));
  float e[4], sum = 0.f;
#pragma unroll
  for (int i = 0; i < 4; i++) { e[i] = __expf(v[i] - m); sum += e[i]; }
#pragma unroll
  for (int off = 32; off; off >>= 1) sum += __shfl_xor(sum, off);
  __syncthreads();
  if ((tid & 63) == 0) red[4 + (tid >> 6)] = sum;
  __syncthreads();
  sum = red[4] + red[5] + red[6] + red[7];
  const float inv = 1.0f / sum;
#pragma unroll
  for (int i = 0; i < 4; i++) out[b * S + tid + i * 256] = e[i] * inv;
}

extern "C" void kernel_launch(void* const* d_in, const int* in_sizes, int n_in,
                              void* d_out, int out_size, void* d_ws, size_t ws_size,
                              hipStream_t stream) {
  const float* enc    = (const float*)d_in[0];  // (S,B,2H)
  const float* hidden = (const float*)d_in[1];  // (B,H)
  // d_in[2] = cell — unused by the reference
  const float* W_attn = (const float*)d_in[3];  // (H,3H)
  const float* b_attn = (const float*)d_in[4];  // (H)
  const float* v_w    = (const float*)d_in[5];  // (H)
  float* out = (float*)d_out;                   // (B,S)

  char* ws = (char*)d_ws;
  float* attn = (float*)ws;                                  // 128 KiB
  float* hp   = (float*)(ws + 131072);                       // 128 KiB
  u16* Web    = (u16*)(ws + 262144);                         // 4 MiB
  u16* encb   = (u16*)(ws + 4456448);                        // 128 MiB (B,S,2H) bf16

  hipMemsetAsync(attn, 0, B * S * sizeof(float), stream);    // ws is 0xAA-poisoned each call
  conv_we_k<<<H, 256, 0, stream>>>(W_attn, Web);
  hproj_k<<<256, 256, 0, stream>>>(hidden, W_attn, b_attn, hp);
  conv_enc_k<<<S * B, 256, 0, stream>>>(enc, encb);
  gemm_8ph_k<<<512, 512, 0, stream>>>(encb, Web, hp, v_w, attn);
  softmax_k<<<B, 256, 0, stream>>>(attn, out);
}